// Round 6
// baseline (649.716 us; speedup 1.0000x reference)
//
#include <hip/hip_runtime.h>
#include <hip/hip_bf16.h>

typedef unsigned short u16;
typedef unsigned int u32;
typedef __attribute__((ext_vector_type(4))) float f32x4;
typedef __attribute__((ext_vector_type(8))) short short8;
typedef __attribute__((ext_vector_type(4))) unsigned short u16x4;
typedef __attribute__((ext_vector_type(2))) unsigned int u32x2;
typedef __attribute__((ext_vector_type(4))) unsigned int u32x4;

// B=32, T=64, I=H=512, V=32000, G=4H=2048, M=T*B=2048
#define LSTM_NBLK 16

static __device__ __forceinline__ u16 f2bf(float f) {
  union { float f; unsigned u; } v; v.f = f;
  unsigned r = v.u + 0x7FFFu + ((v.u >> 16) & 1u);
  return (u16)(r >> 16);
}

static __device__ __forceinline__ void gload_lds16(const void* g, void* l) {
  __builtin_amdgcn_global_load_lds(
      (const __attribute__((address_space(1))) unsigned int*)g,
      (__attribute__((address_space(3))) unsigned int*)l, 16, 0, 0);
}

// --- L3-coherent (cross-XCD) access helpers: bypass L1/L2 ---
static __device__ __forceinline__ u32x4 ld_b128u_sc(const u32* p) {
  u32x4 r;
  asm volatile("global_load_dwordx4 %0, %1, off sc0 sc1"
               : "=v"(r) : "v"(p) : "memory");
  return r;
}
static __device__ __forceinline__ void st_u64_sc(void* p, u32 lo, u32 hi) {
  u32x2 v; v[0] = lo; v[1] = hi;
  asm volatile("global_store_dwordx2 %0, %1, off sc0 sc1"
               :: "v"(p), "v"(v) : "memory");
}
static __device__ __forceinline__ void waitcnt0() {
  asm volatile("s_waitcnt vmcnt(0)" ::: "memory");
  __builtin_amdgcn_sched_barrier(0);
}

// ---------------- prep: casts + transpose + tagged slot0 + h2 slot0 ----------------
__global__ void prep_kernel(const float* __restrict__ iseq, const float* __restrict__ h0,
                            const float* __restrict__ wih, const float* __restrict__ whh,
                            const float* __restrict__ wout,
                            u16* __restrict__ wout_bf, u16* __restrict__ wih_bf,
                            u16* __restrict__ whh_bf, u16* __restrict__ ax,
                            u32* __restrict__ htag, u32* __restrict__ h2u) {
  const int S0 = 4096000;                 // Wout /4
  const int S1 = S0 + 262144;             // Wih /4
  const int S2 = S1 + 262144;             // Whh /4
  const int S3 = S2 + 262144;             // ax /4
  const int S4 = S3 + 4096;               // htag slot 0 (16384 u32 /4)
  const int S5 = S4 + 258048;             // clear tags of slots 1..63
  const int S6 = S5 + 2048;               // h2 slot 0 (8192 u32 /4)
  int u = blockIdx.x * blockDim.x + threadIdx.x;
  int stride = gridDim.x * blockDim.x;
  for (; u < S6; u += stride) {
    if (u < S0) {
      int e = u * 4; f32x4 v = *(const f32x4*)(wout + e);
      u16x4 o; o[0]=f2bf(v[0]); o[1]=f2bf(v[1]); o[2]=f2bf(v[2]); o[3]=f2bf(v[3]);
      *(u16x4*)(wout_bf + e) = o;
    } else if (u < S1) {
      int e = (u - S0) * 4; f32x4 v = *(const f32x4*)(wih + e);
      u16x4 o; o[0]=f2bf(v[0]); o[1]=f2bf(v[1]); o[2]=f2bf(v[2]); o[3]=f2bf(v[3]);
      *(u16x4*)(wih_bf + e) = o;
    } else if (u < S2) {
      int e = (u - S1) * 4; f32x4 v = *(const f32x4*)(whh + e);
      u16x4 o; o[0]=f2bf(v[0]); o[1]=f2bf(v[1]); o[2]=f2bf(v[2]); o[3]=f2bf(v[3]);
      *(u16x4*)(whh_bf + e) = o;
    } else if (u < S3) {
      // A_x[m= t*32+b][k] = iseq[b][t][k]
      int e = (u - S2) * 4; int m = e >> 9; int k = e & 511;
      int b = m & 31; int t = m >> 5;
      f32x4 v = *(const f32x4*)(iseq + ((b * 64 + t) << 9) + k);
      u16x4 o; o[0]=f2bf(v[0]); o[1]=f2bf(v[1]); o[2]=f2bf(v[2]); o[3]=f2bf(v[3]);
      *(u16x4*)(ax + e) = o;
    } else if (u < S4) {
      // htag slot 0 = {tag=1, bf16(h0)}
      int e = (u - S3) * 4; f32x4 v = *(const f32x4*)(h0 + e);
      u32x4 o;
      o[0] = (1u << 16) | f2bf(v[0]); o[1] = (1u << 16) | f2bf(v[1]);
      o[2] = (1u << 16) | f2bf(v[2]); o[3] = (1u << 16) | f2bf(v[3]);
      *(u32x4*)(htag + e) = o;
    } else if (u < S5) {
      // clear tags of slots 1..63
      int e = (u - S4) * 4;
      u32x4 z = {0u, 0u, 0u, 0u};
      *(u32x4*)(htag + 16384 + e) = z;
    } else {
      // h2 slot 0 = bf16(h0) packed pairs
      int v = (u - S5) * 4;               // u32 index, 4 per iter
      int e = v * 2;                      // f32 element index
      f32x4 x0 = *(const f32x4*)(h0 + e);
      f32x4 x1 = *(const f32x4*)(h0 + e + 4);
      u32x4 o;
      o[0] = (((u32)f2bf(x0[1])) << 16) | (u32)f2bf(x0[0]);
      o[1] = (((u32)f2bf(x0[3])) << 16) | (u32)f2bf(x0[2]);
      o[2] = (((u32)f2bf(x1[1])) << 16) | (u32)f2bf(x1[0]);
      o[3] = (((u32)f2bf(x1[3])) << 16) | (u32)f2bf(x1[2]);
      *(u32x4*)(h2u + v) = o;
    }
  }
}

// ---------------- generic C = A*Bw^T + bias GEMM ----------------
// A: [2048][512] bf16 row-major (remap=0) or h2-slot layout (remap=1),
// Bw: [N][512] bf16 row-major, C: [2048][N] f32
__global__ __launch_bounds__(256, 2) void gemm_bt(
    const u16* __restrict__ A, const u16* __restrict__ Bw,
    float* __restrict__ C, const float* __restrict__ bias1,
    const float* __restrict__ bias2, int N, int remap) {
  __shared__ u16 As[2][8192];
  __shared__ u16 Bs[2][8192];
  const int tid = threadIdx.x;
  const int w = tid >> 6, l = tid & 63;
  const int wr = w >> 1, wc = w & 1;
  const int tm = blockIdx.y * 128, tn = blockIdx.x * 128;

  f32x4 acc[4][4];
#pragma unroll
  for (int i = 0; i < 4; ++i)
#pragma unroll
    for (int j = 0; j < 4; ++j) acc[i][j] = (f32x4){0.f, 0.f, 0.f, 0.f};

  auto stage = [&](int buf, int kt) {
#pragma unroll
    for (int i = 0; i < 4; ++i) {
      int r = (w * 4 + i) * 8 + (l >> 3);
      int c16 = (l & 7) ^ (r & 7);  // pre-swizzled source column
      int rowm = tm + r;
      const u16* srca;
      if (remap) {
        // logical A row m -> h_t[b] : slot (m&63)+1, row m>>6
        srca = A + ((rowm & 63) + 1) * 16384 + (rowm >> 6) * 512 + kt * 64 + c16 * 8;
      } else {
        srca = A + rowm * 512 + kt * 64 + c16 * 8;
      }
      gload_lds16(srca, &As[buf][(w * 4 + i) * 512]);
      const u16* srcb = Bw + (tn + r) * 512 + kt * 64 + c16 * 8;
      gload_lds16(srcb, &Bs[buf][(w * 4 + i) * 512]);
    }
  };

  stage(0, 0);
  int buf = 0;
  for (int kt = 0; kt < 8; ++kt) {
    __syncthreads();
    if (kt < 7) stage(buf ^ 1, kt + 1);
#pragma unroll
    for (int kk = 0; kk < 2; ++kk) {
      short8 af[4], bfr[4];
#pragma unroll
      for (int mi = 0; mi < 4; ++mi) {
        int row = wr * 64 + mi * 16 + (l & 15);
        int s = (kk * 4 + (l >> 4)) ^ (row & 7);
        af[mi] = *(const short8*)&As[buf][row * 64 + s * 8];
      }
#pragma unroll
      for (int ni = 0; ni < 4; ++ni) {
        int row = wc * 64 + ni * 16 + (l & 15);
        int s = (kk * 4 + (l >> 4)) ^ (row & 7);
        bfr[ni] = *(const short8*)&Bs[buf][row * 64 + s * 8];
      }
#pragma unroll
      for (int mi = 0; mi < 4; ++mi)
#pragma unroll
        for (int ni = 0; ni < 4; ++ni)
          acc[mi][ni] = __builtin_amdgcn_mfma_f32_16x16x32_bf16(
              af[mi], bfr[ni], acc[mi][ni], 0, 0, 0);
    }
    buf ^= 1;
  }

#pragma unroll
  for (int ni = 0; ni < 4; ++ni) {
    int gcol = tn + wc * 64 + ni * 16 + (l & 15);
    float bv = 0.f;
    if (bias1) bv += bias1[gcol];
    if (bias2) bv += bias2[gcol];
#pragma unroll
    for (int mi = 0; mi < 4; ++mi) {
      int grow0 = tm + wr * 64 + mi * 16 + ((l >> 4) << 2);
      f32x4 a = acc[mi][ni];
#pragma unroll
      for (int q = 0; q < 4; ++q) {
        C[(long long)(grow0 + q) * N + gcol] = a[q] + bv;
      }
    }
  }
}

// ---------------- persistent LSTM recurrence (tagged full-line exchange) ----
// 16 blocks x 512 threads (8 waves). Wave owns 4 j-cols => 16 W_hh rows in
// registers; cell state in registers. Per step: consumer threads poll their
// private 128B tagged chunk (per-u32 tag => no line tearing), stage payloads
// into XOR-swizzled LDS (double-buffered), barrier, MFMA, pointwise -> hloc,
// barrier, repack: plain h2 store (cached) + tagged full-line coherent store
// (fire-and-forget, no drain, no flags). Own slice short-circuits via LDS.
__global__ __launch_bounds__(512, 1) void lstm_persist(
    const u16* __restrict__ whh, const float* __restrict__ xg,
    u16* __restrict__ h2, u32* __restrict__ htag) {
  __shared__ u16 hbuf[2][32 * 512];
  __shared__ u16 hloc[1024];
  const int tid = threadIdx.x;
  const int w = tid >> 6, l = tid & 63;
  const int blk = blockIdx.x;
  const int j0 = (blk * 8 + w) * 4;                // wave's 4 h-columns
  const int c = l & 15;
  const int wrow = (c >> 2) * 512 + j0 + (c & 3);  // W_hh row == gate column
  const int ko = (l >> 4) * 8;
  u32* h2u = (u32*)h2;

  // resident weights: 16 x short8 = 64 VGPRs
  short8 bfr[16];
  const u16* wp = whh + wrow * 512 + ko;
#pragma unroll
  for (int kt = 0; kt < 16; ++kt) bfr[kt] = *(const short8*)(wp + kt * 32);

  const int rq = (l >> 4) * 4;
  const int jj = l & 3;
  const int b0 = l & 15, b1 = 16 + (l & 15);
  const int s0 = b0 & 7;

  // consumer stage mapping: thread covers (row cb, 32 k-cols at ckg*32)
  const int cb = tid & 31;
  const int ckg = tid >> 5;        // 0..15 == producer block index
  const int csw = cb & 7;

  // producer repack mapping: thread stores (row pb, 2 cols at pj*2)
  const int pb = tid >> 4;         // 0..31
  const int pj = tid & 15;         // 0..15

  float creg[2][4];
#pragma unroll
  for (int mt = 0; mt < 2; ++mt)
#pragma unroll
    for (int q = 0; q < 4; ++q) creg[mt][q] = 0.f;

  float xcur[2][4], xnext[2][4];
#pragma unroll
  for (int mt = 0; mt < 2; ++mt)
#pragma unroll
    for (int q = 0; q < 4; ++q)
      xcur[mt][q] = xg[(mt * 16 + rq + q) * 2048 + wrow];

  for (int it = 0; it < 64; ++it) {
    u16* hb = hbuf[it & 1];
    // ---- (A) acquire h_prev chunk ----
    short8 d0, d1, d2, d3;
    if (it > 0 && ckg == blk) {
      // own slice: straight from LDS (written last step, after S2)
      d0 = *(const short8*)&hloc[cb * 32 + 0];
      d1 = *(const short8*)&hloc[cb * 32 + 8];
      d2 = *(const short8*)&hloc[cb * 32 + 16];
      d3 = *(const short8*)&hloc[cb * 32 + 24];
    } else {
      const u32* src = htag + it * 16384 + cb * 512 + ckg * 32;
      const unsigned want = (unsigned)(it + 1);
      u32x4 a0, a1, a2, a3, a4, a5, a6, a7;
      for (;;) {
        a0 = ld_b128u_sc(src +  0); a1 = ld_b128u_sc(src +  4);
        a2 = ld_b128u_sc(src +  8); a3 = ld_b128u_sc(src + 12);
        a4 = ld_b128u_sc(src + 16); a5 = ld_b128u_sc(src + 20);
        a6 = ld_b128u_sc(src + 24); a7 = ld_b128u_sc(src + 28);
        waitcnt0();
        unsigned d = 0;
#pragma unroll
        for (int q2 = 0; q2 < 4; ++q2) {
          d |= (a0[q2] >> 16) ^ want; d |= (a1[q2] >> 16) ^ want;
          d |= (a2[q2] >> 16) ^ want; d |= (a3[q2] >> 16) ^ want;
          d |= (a4[q2] >> 16) ^ want; d |= (a5[q2] >> 16) ^ want;
          d |= (a6[q2] >> 16) ^ want; d |= (a7[q2] >> 16) ^ want;
        }
        if (d == 0) break;  // per-lane early exit (exec-masked loop)
      }
      d0[0]=(short)a0[0]; d0[1]=(short)a0[1]; d0[2]=(short)a0[2]; d0[3]=(short)a0[3];
      d0[4]=(short)a1[0]; d0[5]=(short)a1[1]; d0[6]=(short)a1[2]; d0[7]=(short)a1[3];
      d1[0]=(short)a2[0]; d1[1]=(short)a2[1]; d1[2]=(short)a2[2]; d1[3]=(short)a2[3];
      d1[4]=(short)a3[0]; d1[5]=(short)a3[1]; d1[6]=(short)a3[2]; d1[7]=(short)a3[3];
      d2[0]=(short)a4[0]; d2[1]=(short)a4[1]; d2[2]=(short)a4[2]; d2[3]=(short)a4[3];
      d2[4]=(short)a5[0]; d2[5]=(short)a5[1]; d2[6]=(short)a5[2]; d2[7]=(short)a5[3];
      d3[0]=(short)a6[0]; d3[1]=(short)a6[1]; d3[2]=(short)a6[2]; d3[3]=(short)a6[3];
      d3[4]=(short)a7[0]; d3[5]=(short)a7[1]; d3[6]=(short)a7[2]; d3[7]=(short)a7[3];
    }
    *(short8*)&hb[cb * 512 + (((ckg * 4 + 0) ^ csw) * 8)] = d0;
    *(short8*)&hb[cb * 512 + (((ckg * 4 + 1) ^ csw) * 8)] = d1;
    *(short8*)&hb[cb * 512 + (((ckg * 4 + 2) ^ csw) * 8)] = d2;
    *(short8*)&hb[cb * 512 + (((ckg * 4 + 3) ^ csw) * 8)] = d3;
    __syncthreads();   // S1: hb ready; hloc reads done

    // ---- (B) MFMA: gates = h_prev @ W_hh^T ----
    f32x4 acc0 = (f32x4){0.f, 0.f, 0.f, 0.f};
    f32x4 acc1 = (f32x4){0.f, 0.f, 0.f, 0.f};
#pragma unroll
    for (int kt = 0; kt < 16; ++kt) {
      int x = ((kt * 4 + (l >> 4)) ^ s0) * 8;
      short8 a0 = *(const short8*)&hb[b0 * 512 + x];
      short8 a1 = *(const short8*)&hb[b1 * 512 + x];
      acc0 = __builtin_amdgcn_mfma_f32_16x16x32_bf16(a0, bfr[kt], acc0, 0, 0, 0);
      acc1 = __builtin_amdgcn_mfma_f32_16x16x32_bf16(a1, bfr[kt], acc1, 0, 0, 0);
    }
    if (it < 63) {
#pragma unroll
      for (int mt = 0; mt < 2; ++mt)
#pragma unroll
        for (int q = 0; q < 4; ++q)
          xnext[mt][q] = xg[((it + 1) * 32 + mt * 16 + rq + q) * 2048 + wrow];
    }

    // ---- (C) pointwise LSTM cell -> hloc ----
#pragma unroll
    for (int mt = 0; mt < 2; ++mt) {
#pragma unroll
      for (int q = 0; q < 4; ++q) {
        float av = (mt == 0) ? acc0[q] : acc1[q];
        float gp = av + xcur[mt][q];
        int bl = (l & 48) | jj;
        float xi = __shfl(gp, bl);
        float xf = __shfl(gp, bl | 4);
        float xgg = __shfl(gp, bl | 8);
        float xo = __shfl(gp, bl | 12);
        float is = 1.f / (1.f + __expf(-xi));
        float fs = 1.f / (1.f + __expf(-xf));
        float e2 = __expf(2.f * xgg);
        float gt = 1.f - 2.f / (e2 + 1.f);       // tanh, inf-safe
        float os = 1.f / (1.f + __expf(-xo));
        float cn = fs * creg[mt][q] + is * gt;
        creg[mt][q] = cn;
        float e2c = __expf(2.f * cn);
        float hn = os * (1.f - 2.f / (e2c + 1.f));
        if ((l & 12) == 0) {  // unique (b, j) writer lanes
          int b = mt * 16 + rq + q;
          hloc[b * 32 + w * 4 + jj] = f2bf(hn);
        }
      }
    }
    __syncthreads();   // S2: hloc complete

    // ---- (D) publish: plain h2 (cached) + tagged slot (coherent, no drain) ----
    {
      u32 lo = (u32)hloc[pb * 32 + pj * 2];
      u32 hi = (u32)hloc[pb * 32 + pj * 2 + 1];
      h2u[(it + 1) * 8192 + pb * 256 + blk * 16 + pj] = (hi << 16) | lo;
      if (it < 63) {
        u32 tag = ((u32)(it + 2)) << 16;
        st_u64_sc(htag + (it + 1) * 16384 + pb * 512 + blk * 32 + pj * 2,
                  tag | lo, tag | hi);
      }
    }
    if (it < 63) {
#pragma unroll
      for (int mt = 0; mt < 2; ++mt)
#pragma unroll
        for (int q = 0; q < 4; ++q)
          xcur[mt][q] = xnext[mt][q];
    }
  }
}

extern "C" void kernel_launch(void* const* d_in, const int* in_sizes, int n_in,
                              void* d_out, int out_size, void* d_ws, size_t ws_size,
                              hipStream_t stream) {
  (void)in_sizes; (void)n_in; (void)out_size; (void)ws_size;
  const float* iseq = (const float*)d_in[0];
  const float* h0   = (const float*)d_in[1];
  const float* wih  = (const float*)d_in[2];
  const float* whh  = (const float*)d_in[3];
  const float* bih  = (const float*)d_in[4];
  const float* bhh  = (const float*)d_in[5];
  const float* wout = (const float*)d_in[6];
  const float* bout = (const float*)d_in[7];

  char* ws = (char*)d_ws;
  u16* wout_bf = (u16*)(ws + 0);             // 32,768,000
  u16* wih_bf  = (u16*)(ws + 32768000);      // 2,097,152
  u16* whh_bf  = (u16*)(ws + 34865152);      // 2,097,152
  u16* ax      = (u16*)(ws + 36962304);      // 2,097,152
  u16* h2      = (u16*)(ws + 39059456);      // 65 slots x 32,768 = 2,129,920
  u32* htag    = (u32*)(ws + 41189376);      // 64 slots x 65,536 = 4,194,304
  float* xg    = (float*)(ws + 45383680);    // 16,777,216  (end 62,160,896)
  float* out   = (float*)d_out;

  prep_kernel<<<4096, 256, 0, stream>>>(iseq, h0, wih, whh, wout,
                                        wout_bf, wih_bf, whh_bf, ax,
                                        htag, (u32*)h2);
  // x_gates = A_x @ W_ih^T + b_ih + b_hh   -> xg [2048][2048] f32
  gemm_bt<<<dim3(16, 16), 256, 0, stream>>>(ax, wih_bf, xg, bih, bhh, 2048, 0);
  // persistent recurrence: tagged full-line exchange, 64 steps
  lstm_persist<<<LSTM_NBLK, 512, 0, stream>>>(whh_bf, xg, h2, htag);
  // logits = h @ W_out^T + b_out -> d_out [2048][32000] f32 (A remapped from h2 slots)
  gemm_bt<<<dim3(250, 16), 256, 0, stream>>>(h2, wout_bf, out, bout, nullptr, 32000, 1);
}